// Round 8
// baseline (264.360 us; speedup 1.0000x reference)
//
#include <hip/hip_runtime.h>
#include <hip/hip_fp16.h>
#include <cstdint>
#include <cstddef>
#include <math.h>

#define B_ 2
#define T_ 2048
#define D_ 1024
#define M_ (B_*T_)

// column layout of P (= row layout of W concat), all offsets multiples of 8
#define QO0 0
#define KO0 128
#define WO0 160
#define QO1 168
#define KO1 680
#define WO1 744
#define QO2 752
#define KO2 2800
#define WO2 2928
#define SELO 2944
#define LDN 3072

typedef float f32x16 __attribute__((ext_vector_type(16)));
typedef short bf16x8 __attribute__((ext_vector_type(8)));
typedef unsigned short u16;

__device__ __forceinline__ u16 f2bf(float f) {
    unsigned int u = __float_as_uint(f);
    unsigned int r = (u + 0x7fffu + ((u >> 16) & 1u)) >> 16;   // RNE
    return (u16)r;
}
__device__ __forceinline__ float bf2f(u16 b) {
    return __uint_as_float(((unsigned int)b) << 16);
}

// async global->LDS, 16B per lane, dest = wave-uniform base + lane*16
__device__ __forceinline__ void gload16(const void* g, void* l) {
    __builtin_amdgcn_global_load_lds(
        (const __attribute__((address_space(1))) unsigned int*)g,
        (__attribute__((address_space(3))) unsigned int*)l,
        16, 0, 0);
}

// Bank-conflict-free 16row x 32col u16 plane-slice staging with XOR swizzle.
// LDS slot s of row r holds logical 8-u16 chunk s ^ tkey(r), tkey(r)=(r&3)^((r>>2)&3).
__device__ __forceinline__ void stage_plane(const u16* src_base, int row_stride, int k0,
                                            int rg, int lane, u16* dst) {
    int rl  = lane >> 2;
    int row = rg * 16 + rl;
    int q   = (lane & 3) ^ (rl & 3) ^ ((rl >> 2) & 3);
    const u16* s = src_base + (size_t)row * row_stride + k0 + q * 8;
    gload16(s, dst + rg * 512);
}

// ---------------- pass 1: partial sums over t (16-row chunks) + x -> bf16 ----------------
__global__ void stats1(const float* __restrict__ x, float* __restrict__ part,
                       float* __restrict__ part2, u16* __restrict__ Xh) {
    int d  = blockIdx.x * 256 + threadIdx.x;
    int tc = blockIdx.y;                       // 0..127
    int b  = blockIdx.z;
    size_t base = (size_t)b * T_ * D_ + (size_t)tc * 16 * D_ + d;
    float s = 0.f, s2 = 0.f;
#pragma unroll
    for (int t = 0; t < 16; ++t) {
        float v = x[base + (size_t)t * D_];
        s += v; s2 += v * v;
        Xh[base + (size_t)t * D_] = f2bf(v);
    }
    part [(b * 128 + tc) * D_ + d] = s;
    part2[(b * 128 + tc) * D_ + d] = s2;
}

// ---------------- pass 2a: finalize mean+std per (b,d) ----------------
__global__ void stats2a(const float* __restrict__ part, const float* __restrict__ part2,
                        float* __restrict__ MS) {
    __shared__ float r1[4][64], r2[4][64];
    int blk = blockIdx.x;                      // 0..31
    int b = blk >> 4, dg = blk & 15;
    int tid = threadIdx.x;
    int dl = tid & 63, sl = tid >> 6;
    int d = dg * 64 + dl;
    float s = 0.f, s2 = 0.f;
    for (int i = sl; i < 128; i += 4) {
        s  += part [(b * 128 + i) * D_ + d];
        s2 += part2[(b * 128 + i) * D_ + d];
    }
    r1[sl][dl] = s; r2[sl][dl] = s2;
    __syncthreads();
    if (sl == 0) {
        s  = r1[0][dl] + r1[1][dl] + r1[2][dl] + r1[3][dl];
        s2 = r2[0][dl] + r2[1][dl] + r2[2][dl] + r2[3][dl];
        float mean = s / (float)T_;
        float var  = (s2 - (float)T_ * mean * mean) / (float)(T_ - 1);
        MS[b * D_ + d] = mean + sqrtf(fmaxf(var, 0.f));
    }
}

// ---------------- pass 2b: msd[b][j] = MS[b,:].w1[j,:], s1[j] = sum w1[j,:] -------------
__global__ void msdot(const float* __restrict__ MS, const float* __restrict__ w1,
                      float* __restrict__ msd, float* __restrict__ s1) {
    __shared__ float rA[4], rW[4];
    int blk = blockIdx.x;                      // 0..127
    int b = blk >> 6, j = blk & 63;
    int tid = threadIdx.x;
    float4 m = *(const float4*)(MS + (size_t)b * D_ + tid * 4);
    float4 w = *(const float4*)(w1 + (size_t)j * D_ + tid * 4);
    float am = m.x * w.x + m.y * w.y + m.z * w.z + m.w * w.w;
    float aw = w.x + w.y + w.z + w.w;
    for (int off = 32; off; off >>= 1) {
        am += __shfl_down(am, off);
        aw += __shfl_down(aw, off);
    }
    int wv = tid >> 6, ln = tid & 63;
    if (ln == 0) { rA[wv] = am; rW[wv] = aw; }
    __syncthreads();
    if (tid == 0) {
        msd[b * 64 + j] = rA[0] + rA[1] + rA[2] + rA[3];
        if (b == 0) s1[j] = rW[0] + rW[1] + rW[2] + rW[3];
    }
}

// ---------------- weight concat -> bf16: Wh[3072][1024] ----------------
__global__ void split_w(const float* __restrict__ qw0, const float* __restrict__ kw0,
                        const float* __restrict__ ww0, const float* __restrict__ qw1,
                        const float* __restrict__ kw1, const float* __restrict__ ww1,
                        const float* __restrict__ qw2, const float* __restrict__ kw2,
                        const float* __restrict__ ww2, const float* __restrict__ w1s,
                        u16* __restrict__ Wh) {
    int row = blockIdx.x;
    int col = threadIdx.x * 4;
    const float* src = nullptr;
    if      (row < 128)  src = qw0 + (size_t)row * D_;
    else if (row < 160)  src = kw0 + (size_t)(row - 128) * D_;
    else if (row < 164)  src = ww0 + (size_t)(row - 160) * D_;
    else if (row < 168)  src = nullptr;
    else if (row < 680)  src = qw1 + (size_t)(row - 168) * D_;
    else if (row < 744)  src = kw1 + (size_t)(row - 680) * D_;
    else if (row < 752)  src = ww1 + (size_t)(row - 744) * D_;
    else if (row < 2800) src = qw2 + (size_t)(row - 752) * D_;
    else if (row < 2928) src = kw2 + (size_t)(row - 2800) * D_;
    else if (row < 2944) src = ww2 + (size_t)(row - 2928) * D_;
    else if (row < 3008) src = w1s + (size_t)(row - 2944) * D_;
    float4 v = src ? *(const float4*)(src + col) : make_float4(0.f, 0.f, 0.f, 0.f);
    ushort4 h;
    h.x = f2bf(v.x); h.y = f2bf(v.y); h.z = f2bf(v.z); h.w = f2bf(v.w);
    *(ushort4*)&Wh[(size_t)row * D_ + col] = h;
}

// ---------------- projection GEMM, m97-style: BK=64 single-buffered ----------------
__global__ __launch_bounds__(256, 3) void proj_gemm(
    const u16* __restrict__ Xh, const u16* __restrict__ Wh, u16* __restrict__ Ph) {
    __shared__ u16 As[8192], Bs[8192];   // 128 rows x 64 cols (2 planes of 32)
    int tid = threadIdx.x;
    int wave = tid >> 6, lane = tid & 63;
    int bm = blockIdx.x * 128, bn = blockIdx.y * 128;
    int wt = wave >> 1, wn = wave & 1;
    int fm = lane & 31, hv = lane >> 5;
    int tkey = (fm & 3) ^ ((fm >> 2) & 3);
    f32x16 acc[2][2];
#pragma unroll
    for (int i = 0; i < 2; ++i)
#pragma unroll
        for (int j = 0; j < 2; ++j)
#pragma unroll
            for (int r = 0; r < 16; ++r) acc[i][j][r] = 0.f;

    const u16* xh = Xh + (size_t)bm * D_;
    const u16* wh = Wh + (size_t)bn * D_;

    for (int kc = 0; kc < 16; ++kc) {
        int k0 = kc * 64;
#pragma unroll
        for (int i = 0; i < 8; ++i) {
            int j = wave * 8 + i;
            int mat = j >> 4;
            int pl  = (j >> 3) & 1;
            int rg  = j & 7;
            stage_plane(mat ? wh : xh, D_, k0 + pl * 32, rg, lane,
                        (mat ? Bs : As) + pl * 4096);
        }
        __syncthreads();
#pragma unroll
        for (int ks = 0; ks < 4; ++ks) {
            int pl = ks >> 1;
            int slot8 = (((ks & 1) * 2 + hv) ^ tkey) * 8;
            bf16x8 a_h[2], b_h[2];
#pragma unroll
            for (int t = 0; t < 2; ++t) {
                a_h[t] = *(const bf16x8*)&As[pl * 4096 + (wt * 64 + t * 32 + fm) * 32 + slot8];
                b_h[t] = *(const bf16x8*)&Bs[pl * 4096 + (wn * 64 + t * 32 + fm) * 32 + slot8];
            }
#pragma unroll
            for (int ti = 0; ti < 2; ++ti)
#pragma unroll
                for (int tj = 0; tj < 2; ++tj)
                    acc[ti][tj] = __builtin_amdgcn_mfma_f32_32x32x16_bf16(a_h[ti], b_h[tj], acc[ti][tj], 0, 0, 0);
        }
        __syncthreads();
    }
#pragma unroll
    for (int ti = 0; ti < 2; ++ti)
#pragma unroll
        for (int tj = 0; tj < 2; ++tj)
#pragma unroll
            for (int r = 0; r < 16; ++r) {
                int row = bm + wt * 64 + ti * 32 + (r & 3) + 8 * (r >> 2) + 4 * hv;
                int col = bn + wn * 64 + tj * 32 + fm;
                Ph[(size_t)row * LDN + col] = f2bf(acc[ti][tj][r]);
            }
}

// ---------------- selector layers 2-3 + softmax + WP=w*prob (f16) ----------
__global__ void selector2(const u16* __restrict__ Ph,
                          const float* __restrict__ msd, const float* __restrict__ s1,
                          const float* __restrict__ b1, const float* __restrict__ w2,
                          const float* __restrict__ b2, const float* __restrict__ w3,
                          const float* __restrict__ b3, __half* __restrict__ WP) {
    __shared__ float h1s[4][64];
    __shared__ float h2s[4][64];
    __shared__ float lg[4][3];
    int tid = threadIdx.x;
    int slot = tid >> 6, j = tid & 63;
    int bt = blockIdx.x * 4 + slot;
    int b = bt >> 11, t = bt & 2047;
    size_t pidx = (size_t)bt * LDN + SELO + j;
    float v = bf2f(Ph[pidx])
            + msd[b * 64 + j] + 0.1f * ((float)t / (float)T_) * s1[j] + b1[j];
    h1s[slot][j] = fmaxf(v, 0.f);
    __syncthreads();
    float a2 = b2[j];
#pragma unroll 8
    for (int d = 0; d < 64; ++d) a2 = fmaf(h1s[slot][d], w2[j * 64 + d], a2);
    h2s[slot][j] = fmaxf(a2, 0.f);
    __syncthreads();
    if (j < 3) {
        float a3 = b3[j];
        for (int d = 0; d < 64; ++d) a3 = fmaf(h2s[slot][d], w3[j * 64 + d], a3);
        lg[slot][j] = a3;
    }
    __syncthreads();
    if (j < 28) {
        float m = fmaxf(lg[slot][0], fmaxf(lg[slot][1], lg[slot][2]));
        float e0 = expf(lg[slot][0] - m), e1 = expf(lg[slot][1] - m), e2 = expf(lg[slot][2] - m);
        float inv = 1.f / (e0 + e1 + e2);
        int wcol = (j < 4) ? (WO0 + j) : ((j < 12) ? (WO1 + j - 4) : (WO2 + j - 12));
        float p = ((j < 4) ? e0 : ((j < 12) ? e1 : e2)) * inv;
        float w = bf2f(Ph[(size_t)bt * LDN + wcol]);
        WP[(size_t)(b * 28 + j) * T_ + t] = __float2half(w * p);
    }
}

__device__ __forceinline__ int qcol_of(int c) {
    if (c < 2)  return QO0 + c * 64;
    if (c < 10) return QO1 + (c - 2) * 64;
    return QO2 + (c - 10) * 64;
}

// ---------------- fused relu-attention score kernel: K fragments in registers -----------
// block 128(t) x 64(s); 4 waves of 32x64; Q streamed through 32KB LDS dbuf; 12 waves/CU
__global__ __launch_bounds__(256, 3) void score_kernel(
    const u16* __restrict__ Ph, const __half* __restrict__ WP, float* __restrict__ out) {
    __shared__ u16 QsF[16384];          // 2 bufs x 2 planes x [128][32]  (32 KB)
    __shared__ __half wpL[3584];        // [28][128]  (7 KB)
    int tid = threadIdx.x;
    int wave = tid >> 6, lane = tid & 63;
    int fm = lane & 31, hv = lane >> 5;
    int tkey = (fm & 3) ^ ((fm >> 2) & 3);

    // XCD swizzle: 4 q-tiles per XCD, s varies fastest within an XCD
    int n = blockIdx.x;                 // 0..1023
    int qt = (n & 7) * 4 + ((n >> 8) & 3);
    int b = qt >> 4, t0 = (qt & 15) * 128;
    int s0 = ((n >> 3) & 31) * 64;

    const u16* Pq = Ph + (size_t)(b * T_ + t0) * LDN;
    const u16* Pk = Ph + (size_t)(b * T_ + s0) * LDN;

    auto stageQ = [&](int buf, int qcol) {
#pragma unroll
        for (int i = 0; i < 4; ++i) {
            int j = wave * 4 + i;            // 16 jobs: 2 planes x 8 row-groups
            int pl = j >> 3, rg = j & 7;
            stage_plane(Pq, LDN, qcol + pl * 32, rg, lane, &QsF[buf * 8192 + pl * 4096]);
        }
    };

    // ---- prologue: stage cfg0 (KO0) + cfg1 (KO1, KO1+32) K planes (64 s-rows each) + wp
#pragma unroll
    for (int i = 0; i < 3; ++i) {
        int j = i * 4 + wave;                // 12 jobs
        int pl = j >> 2, rg = j & 3;
        int col = (pl == 0) ? KO0 : ((pl == 1) ? KO1 : (KO1 + 32));
        stage_plane(Pk, LDN, col, rg, lane, &QsF[pl * 2048]);
    }
#pragma unroll
    for (int i = 0; i < 2; ++i) {
        int j = i * 4 + wave;
        if (j < 7) {
            const __half* src = WP + (size_t)(b * 28 + j * 4 + (lane >> 4)) * T_ + t0 + (lane & 15) * 8;
            gload16(src, (u16*)wpL + j * 512);
        }
    }
    __syncthreads();
    // K fragments -> registers (B-operand: row = s-col = tj*32+fm, k chunk = half*2+hv)
    bf16x8 k0f[2][2], k1f[2][2][2];
#pragma unroll
    for (int h = 0; h < 2; ++h)
#pragma unroll
        for (int tj = 0; tj < 2; ++tj) {
            int slot8 = ((h * 2 + hv) ^ tkey) * 8;
            int ro = (tj * 32 + fm) * 32 + slot8;
            k0f[h][tj]    = *(const bf16x8*)&QsF[ro];
            k1f[0][h][tj] = *(const bf16x8*)&QsF[2048 + ro];
            k1f[1][h][tj] = *(const bf16x8*)&QsF[4096 + ro];
        }
    __syncthreads();
    stageQ(0, QO0);

    f32x16 outacc[2], dots[2], Z16;
#pragma unroll
    for (int r = 0; r < 16; ++r) Z16[r] = 0.f;
#pragma unroll
    for (int tj = 0; tj < 2; ++tj)
#pragma unroll
        for (int r = 0; r < 16; ++r) { outacc[tj][r] = 0.f; dots[tj][r] = 0.f; }

    auto qread = [&](const u16* qb, int pl, int half) -> bf16x8 {
        int slot8 = ((half * 2 + hv) ^ tkey) * 8;
        return *(const bf16x8*)&qb[pl * 4096 + (wave * 32 + fm) * 32 + slot8];
    };
    auto epi = [&](int g) {
        int rowbase = wave * 32 + 4 * hv;
#pragma unroll
        for (int rq = 0; rq < 4; ++rq) {
            const __half2* wp2 = (const __half2*)&wpL[g * 128 + rowbase + rq * 8];
            float2 f01 = __half22float2(wp2[0]);
            float2 f23 = __half22float2(wp2[1]);
            float wv[4] = {f01.x, f01.y, f23.x, f23.y};
#pragma unroll
            for (int tj = 0; tj < 2; ++tj)
#pragma unroll
                for (int r2 = 0; r2 < 4; ++r2) {
                    int r = rq * 4 + r2;
                    outacc[tj][r] += fmaxf(dots[tj][r], 0.f) * wv[r2];
                }
        }
    };

    // cfg0: phases 0,1 — two d=32 heads per phase, K = k0f
#pragma unroll
    for (int c = 0; c < 2; ++c) {
        __syncthreads();
        stageQ((c + 1) & 1, qcol_of(c + 1));
        const u16* qb = &QsF[(c & 1) * 8192];
        bf16x8 q;
        q = qread(qb, 0, 0);
        dots[0] = __builtin_amdgcn_mfma_f32_32x32x16_bf16(q, k0f[0][0], Z16, 0, 0, 0);
        dots[1] = __builtin_amdgcn_mfma_f32_32x32x16_bf16(q, k0f[0][1], Z16, 0, 0, 0);
        q = qread(qb, 0, 1);
        dots[0] = __builtin_amdgcn_mfma_f32_32x32x16_bf16(q, k0f[1][0], dots[0], 0, 0, 0);
        dots[1] = __builtin_amdgcn_mfma_f32_32x32x16_bf16(q, k0f[1][1], dots[1], 0, 0, 0);
        epi(2 * c);
        q = qread(qb, 1, 0);
        dots[0] = __builtin_amdgcn_mfma_f32_32x32x16_bf16(q, k0f[0][0], Z16, 0, 0, 0);
        dots[1] = __builtin_amdgcn_mfma_f32_32x32x16_bf16(q, k0f[0][1], Z16, 0, 0, 0);
        q = qread(qb, 1, 1);
        dots[0] = __builtin_amdgcn_mfma_f32_32x32x16_bf16(q, k0f[1][0], dots[0], 0, 0, 0);
        dots[1] = __builtin_amdgcn_mfma_f32_32x32x16_bf16(q, k0f[1][1], dots[1], 0, 0, 0);
        epi(2 * c + 1);
    }
    // cfg1: phases 2..9 — one d=64 head per phase, K = k1f
    for (int h = 0; h < 8; ++h) {
        int c = 2 + h;
        __syncthreads();
        if (c < 9) stageQ((c + 1) & 1, qcol_of(c + 1));
        else {
            // c==9: stage cfg2 K planes (4 x 64 rows) into buf 0 (phase 9 reads buf 1)
#pragma unroll
            for (int i = 0; i < 4; ++i) {
                int j = wave * 4 + i;        // 16 jobs
                int pl = j >> 2, rg = j & 3;
                stage_plane(Pk, LDN, KO2 + pl * 32, rg, lane, &QsF[pl * 2048]);
            }
        }
        const u16* qb = &QsF[(c & 1) * 8192];
        bf16x8 q;
        q = qread(qb, 0, 0);
        dots[0] = __builtin_amdgcn_mfma_f32_32x32x16_bf16(q, k1f[0][0][0], Z16, 0, 0, 0);
        dots[1] = __builtin_amdgcn_mfma_f32_32x32x16_bf16(q, k1f[0][0][1], Z16, 0, 0, 0);
        q = qread(qb, 0, 1);
        dots[0] = __builtin_amdgcn_mfma_f32_32x32x16_bf16(q, k1f[0][1][0], dots[0], 0, 0, 0);
        dots[1] = __builtin_amdgcn_mfma_f32_32x32x16_bf16(q, k1f[0][1][1], dots[1], 0, 0, 0);
        q = qread(qb, 1, 0);
        dots[0] = __builtin_amdgcn_mfma_f32_32x32x16_bf16(q, k1f[1][0][0], dots[0], 0, 0, 0);
        dots[1] = __builtin_amdgcn_mfma_f32_32x32x16_bf16(q, k1f[1][0][1], dots[1], 0, 0, 0);
        q = qread(qb, 1, 1);
        dots[0] = __builtin_amdgcn_mfma_f32_32x32x16_bf16(q, k1f[1][1][0], dots[0], 0, 0, 0);
        dots[1] = __builtin_amdgcn_mfma_f32_32x32x16_bf16(q, k1f[1][1][1], dots[1], 0, 0, 0);
        epi(4 + h);
    }
    // transition: read cfg2 K fragments, restart Q streaming
    __syncthreads();
    bf16x8 k2f[4][2][2];
#pragma unroll
    for (int p = 0; p < 4; ++p)
#pragma unroll
        for (int h = 0; h < 2; ++h)
#pragma unroll
            for (int tj = 0; tj < 2; ++tj) {
                int slot8 = ((h * 2 + hv) ^ tkey) * 8;
                k2f[p][h][tj] = *(const bf16x8*)&QsF[p * 2048 + (tj * 32 + fm) * 32 + slot8];
            }
    __syncthreads();
    stageQ(0, qcol_of(10));
    // cfg2: 16 heads x 2 phases (d=128), K = k2f
    for (int h = 0; h < 16; ++h) {
        int c = 10 + 2 * h;
        __syncthreads();
        stageQ(1, qcol_of(c + 1));
        const u16* qb = &QsF[0];
        bf16x8 q;
        q = qread(qb, 0, 0);
        dots[0] = __builtin_amdgcn_mfma_f32_32x32x16_bf16(q, k2f[0][0][0], Z16, 0, 0, 0);
        dots[1] = __builtin_amdgcn_mfma_f32_32x32x16_bf16(q, k2f[0][0][1], Z16, 0, 0, 0);
        q = qread(qb, 0, 1);
        dots[0] = __builtin_amdgcn_mfma_f32_32x32x16_bf16(q, k2f[0][1][0], dots[0], 0, 0, 0);
        dots[1] = __builtin_amdgcn_mfma_f32_32x32x16_bf16(q, k2f[0][1][1], dots[1], 0, 0, 0);
        q = qread(qb, 1, 0);
        dots[0] = __builtin_amdgcn_mfma_f32_32x32x16_bf16(q, k2f[1][0][0], dots[0], 0, 0, 0);
        dots[1] = __builtin_amdgcn_mfma_f32_32x32x16_bf16(q, k2f[1][0][1], dots[1], 0, 0, 0);
        q = qread(qb, 1, 1);
        dots[0] = __builtin_amdgcn_mfma_f32_32x32x16_bf16(q, k2f[1][1][0], dots[0], 0, 0, 0);
        dots[1] = __builtin_amdgcn_mfma_f32_32x32x16_bf16(q, k2f[1][1][1], dots[1], 0, 0, 0);
        __syncthreads();
        if (h < 15) stageQ(0, qcol_of(c + 2));
        const u16* qc = &QsF[8192];
        q = qread(qc, 0, 0);
        dots[0] = __builtin_amdgcn_mfma_f32_32x32x16_bf16(q, k2f[2][0][0], dots[0], 0, 0, 0);
        dots[1] = __builtin_amdgcn_mfma_f32_32x32x16_bf16(q, k2f[2][0][1], dots[1], 0, 0, 0);
        q = qread(qc, 0, 1);
        dots[0] = __builtin_amdgcn_mfma_f32_32x32x16_bf16(q, k2f[2][1][0], dots[0], 0, 0, 0);
        dots[1] = __builtin_amdgcn_mfma_f32_32x32x16_bf16(q, k2f[2][1][1], dots[1], 0, 0, 0);
        q = qread(qc, 1, 0);
        dots[0] = __builtin_amdgcn_mfma_f32_32x32x16_bf16(q, k2f[3][0][0], dots[0], 0, 0, 0);
        dots[1] = __builtin_amdgcn_mfma_f32_32x32x16_bf16(q, k2f[3][0][1], dots[1], 0, 0, 0);
        q = qread(qc, 1, 1);
        dots[0] = __builtin_amdgcn_mfma_f32_32x32x16_bf16(q, k2f[3][1][0], dots[0], 0, 0, 0);
        dots[1] = __builtin_amdgcn_mfma_f32_32x32x16_bf16(q, k2f[3][1][1], dots[1], 0, 0, 0);
        epi(12 + h);
    }

#pragma unroll
    for (int tj = 0; tj < 2; ++tj)
#pragma unroll
        for (int r = 0; r < 16; ++r) {
            int trow = wave * 32 + (r & 3) + 8 * (r >> 2) + 4 * hv;
            out[(size_t)(b * T_ + t0 + trow) * T_ + s0 + tj * 32 + fm] = outacc[tj][r];
        }
}

extern "C" void kernel_launch(void* const* d_in, const int* in_sizes, int n_in,
                              void* d_out, int out_size, void* d_ws, size_t ws_size,
                              hipStream_t stream) {
    const float* x   = (const float*)d_in[0];
    const float* w1  = (const float*)d_in[1];
    const float* b1  = (const float*)d_in[2];
    const float* w2  = (const float*)d_in[3];
    const float* b2  = (const float*)d_in[4];
    const float* w3  = (const float*)d_in[5];
    const float* b3  = (const float*)d_in[6];
    const float* qw0 = (const float*)d_in[7];
    const float* kw0 = (const float*)d_in[8];
    const float* ww0 = (const float*)d_in[9];
    const float* qw1 = (const float*)d_in[10];
    const float* kw1 = (const float*)d_in[11];
    const float* ww1 = (const float*)d_in[12];
    const float* qw2 = (const float*)d_in[13];
    const float* kw2 = (const float*)d_in[14];
    const float* ww2 = (const float*)d_in[15];
    float* out = (float*)d_out;

    float* fb = (float*)d_ws;
    float* PA  = fb; fb += (size_t)B_ * 128 * D_;   // 1 MB
    float* PA2 = fb; fb += (size_t)B_ * 128 * D_;   // 1 MB
    float* MS  = fb; fb += (size_t)B_ * D_;
    float* MSD = fb; fb += 128;
    float* S1  = fb; fb += 64;
    __half* WP = (__half*)fb; fb += (size_t)B_ * 28 * T_ / 2;
    u16* ub = (u16*)fb;
    u16* Wh = ub; ub += (size_t)LDN * D_;      // 6.3 MB
    u16* Xh = ub; ub += (size_t)M_ * D_;       // 8 MB
    u16* Ph = ub; ub += (size_t)M_ * LDN;      // 25 MB

    stats1<<<dim3(D_ / 256, 128, B_), 256, 0, stream>>>(x, PA, PA2, Xh);
    stats2a<<<dim3(B_ * 16), 256, 0, stream>>>(PA, PA2, MS);
    msdot<<<dim3(B_ * 64), 256, 0, stream>>>(MS, w1, MSD, S1);
    split_w<<<dim3(LDN), 256, 0, stream>>>(qw0, kw0, ww0, qw1, kw1, ww1,
                                           qw2, kw2, ww2, w1, Wh);
    proj_gemm<<<dim3(M_ / 128, LDN / 128), 256, 0, stream>>>(Xh, Wh, Ph);
    selector2<<<dim3(M_ / 4), 256, 0, stream>>>(Ph, MSD, S1, b1, w2, b2, w3, b3, WP);
    score_kernel<<<dim3(1024), 256, 0, stream>>>(Ph, WP, out);
}